// Round 11
// baseline (13738.344 us; speedup 1.0000x reference)
//
#include <hip/hip_runtime.h>
#include <cstdint>
#include <cstddef>

// Problem constants (match reference)
#define B_    64
#define C_    128
#define T_    500
#define NRES  2048
#define NCLS  10

// Kernel org: 256 wgs (one per CU), 1024 threads = 16 waves.
// r11 wave map: wave (il, p); wid = tid>>6, il = wid&7, p = wid>>3.
// p selects the BLOCK-PAIR {2p, 2p+1}; lane l: blk = 2p+(l&1),
// bat0 = l&~1, bat1 = l|1 (each wave covers ALL 64 batches).
// => each wave touches only 2 weight streams: G2 weight feed drops from
// 2048 to 1024 ds_read_b128 per CU per step (the r10 LDS-pipe dominator;
// waves (il,0)/(il,1) previously read the identical row twice).
// Fold ((b0+b1)+b2)+b3 now crosses waves: p=0 folds s01 = rn(b0+b1)
// (commutative-exact) -> s01buf; barrier E; p=1 computes
// g2 = rn(rn(s01+a2)+a3), then LIF at lane=bat (full-64 ballot, one 8-B
// gm store per neuron). G1(t+1) on p=1 waves in the poll window;
// classifier partials on the otherwise-idle p=0 waves.
#define NWG   256
#define SL    8
#define NT    1024
#define WROW  520              // skewed words per 512-block row
#define WPIT  (4 * WROW)       // words per neuron row in LDS
#define XSP   132              // xs row pitch (words): 16-B aligned float4 rows

// BIT-EXACT MODEL (validated, absmax 0.0): G1: ascending fmaf chain (K=128).
// G2: KC=512 blocks [512,512,512,512], each an ascending masked rn-add chain
// starting at 0, folded left-to-right ((b0+b1)+b2)+b3.
// LIF: v = rn(rn(0.9f*v) + rn(g1+g2)). DO NOT CHANGE THE ARITHMETIC.
// Cross-wave fold exactness: s01 = rn(b0+b1) = rn(b1+b0) (IEEE add is
// commutative); then rn(rn(s01+a2)+a3) is the exact original order.

// d_ws layout
#define WS_MASK0   0            // 16 KB: gm buf0 (4096 words: j*2+h)
#define WS_MASK1   16384        // 16 KB: gm buf1
#define WS_FLAG    32768        // 16 flags, 1024 B apart (16 KB)
#define WS_ARR     49152        // 256 arrival slots, 16 B apart (4 KB)
#define WS_WORDS   13312        // zero through 53248 B
#define NFLAG      16
#define CHKWG      (NWG - 1)

typedef float v2f __attribute__((ext_vector_type(2)));

struct SMem {
  float    WtT2[SL][WPIT];          // 66560 B : skewed W_res rows
  float    WinT2[SL][C_];           //  4096 B : W_in rows
  float    xs[B_][XSP];             // 33792 B : x[:, :, t], single buffer
  unsigned maskb[2][B_][65];        // 33280 B : bat-major spike words, 2 bufs
  float    s01buf[SL][68];          //  2176 B : rn(b0+b1) per (il, bat)
  double   clfred2[2][NCLS];        //   160 B : per-class partials, 2 bufs
};                                   // total ~140064 B => 1 wg/CU (grid = 256)

__global__ void zero_ws_kernel(unsigned* __restrict__ p, int n) {
  int i = blockIdx.x * blockDim.x + threadIdx.x;
  if (i < n) p[i] = 0u;
}

// packed masked add: lanes' bat0/bat1 chains advance together.
// bfe(sign-extend bit)x2 + and x2 + <2 x float> fadd (RN per elem, bit-exact).
#define ACC2(ACC, WB, M0, M1, JB) do {                                        \
  const unsigned _lo = (unsigned)(((int)((M0) << (31 - (JB)))) >> 31) & (WB); \
  const unsigned _hi = (unsigned)(((int)((M1) << (31 - (JB)))) >> 31) & (WB); \
  v2f _m; _m.x = __uint_as_float(_lo); _m.y = __uint_as_float(_hi);           \
  (ACC) = (ACC) + _m;                                                         \
} while (0)

// one step of the 32x32 bit-matrix transpose ladder (periodic masks)
#define BT_STEP(X, D, MLO) do {                                            \
  const unsigned _y = (unsigned)__shfl_xor((int)(X), (D), 64);             \
  (X) = (b & (D)) ? (((X) & ~(MLO)) | ((_y >> (D)) & (MLO)))               \
                  : (((X) & (MLO)) | ((_y << (D)) & ~(MLO)));              \
} while (0)

#define BT_ALL(X) do {                 \
  BT_STEP(X, 16, 0x0000FFFFu);         \
  BT_STEP(X,  8, 0x00FF00FFu);         \
  BT_STEP(X,  4, 0x0F0F0F0Fu);         \
  BT_STEP(X,  2, 0x33333333u);         \
  BT_STEP(X,  1, 0x55555555u);         \
} while (0)

__device__ __forceinline__ float g1_compute(const float* __restrict__ winrow,
                                            const float* __restrict__ xrow) {
  float g1 = 0.f;
  const float4* __restrict__ winp = (const float4*)winrow;
  const float4* __restrict__ xrp  = (const float4*)xrow;
  #pragma unroll 8
  for (int cq = 0; cq < 32; ++cq) {
    const float4 wv = winp[cq];
    const float4 xq = xrp[cq];
    g1 = fmaf(xq.x, wv.x, g1);
    g1 = fmaf(xq.y, wv.y, g1);
    g1 = fmaf(xq.z, wv.z, g1);
    g1 = fmaf(xq.w, wv.w, g1);
  }
  return g1;
}

__global__ void __launch_bounds__(NT, 4)
reservoir_kernel(const float* __restrict__ x, const float* __restrict__ Win,
                 const float* __restrict__ Wres, const float* __restrict__ Wclf,
                 float* __restrict__ out, unsigned char* __restrict__ ws) {
  __shared__ SMem sm;
  const int w   = blockIdx.x;
  const int tid = threadIdx.x;
  const int b   = tid & 63;          // lane index (= bat in p=1 waves)
  const int wid = tid >> 6;          // wave index 0..15
  const int il  = wid & 7;           // neuron within wg
  const int p   = wid >> 3;          // block-pair selector {2p, 2p+1}
  const int blk = 2 * p + (b & 1);   // G2: block owned by this lane
  const int bat0 = b & ~1;           // G2: even batch of this lane's pair
  const int bat1 = b | 1;            // G2: odd batch
  const int iu  = __builtin_amdgcn_readfirstlane(w * SL + il);

  unsigned* gm0  = (unsigned*)(ws + WS_MASK0);
  unsigned* gm1  = (unsigned*)(ws + WS_MASK1);
  unsigned* flgb = (unsigned*)(ws + WS_FLAG);
  unsigned* arr  = (unsigned*)(ws + WS_ARR);
  unsigned* myflag = flgb + (w & (NFLAG - 1)) * 256;   // 1024-B spacing

  // ---- one-time: stage skewed W_res rows (16 float4 per thread) ----
  {
    const int j0 = tid * 16;
    #pragma unroll
    for (int r4 = 0; r4 < 4; ++r4) {
      const int j   = j0 + r4 * 4;
      const int il2 = j >> 11;
      const int pos = j & 2047;
      const int bk  = pos >> 9;
      const int s   = pos & 511;
      const float4 v4 = *(const float4*)(Wres + (size_t)(w * SL + il2) * NRES + pos);
      *(float4*)(&sm.WtT2[il2][bk * WROW + s]) = v4;
    }
  }
  {
    const int il2 = tid >> 7, c = tid & 127;
    sm.WinT2[il2][c] = Win[(size_t)(w * SL + il2) * C_ + c];
  }

  float v = 0.f;                   // reservoir membrane (p=1 waves, lane=bat)
  int   cntr = 0;
  double vc = 0.0;                 // classifier membrane
  int   cntc = 0;

  // prologue: stage xs(0); prefetch x(:,:,1) into xv
  float xv[8];
  {
    const int p0 = tid * 8;
    float tmp[8];
    #pragma unroll
    for (int r = 0; r < 8; ++r) tmp[r] = x[(size_t)(p0 + r) * T_ + 0];
    float4 fa, fb;
    fa.x = tmp[0]; fa.y = tmp[1]; fa.z = tmp[2]; fa.w = tmp[3];
    fb.x = tmp[4]; fb.y = tmp[5]; fb.z = tmp[6]; fb.w = tmp[7];
    const int row = p0 >> 7, col = p0 & 127;
    *(float4*)(&sm.xs[row][col])     = fa;
    *(float4*)(&sm.xs[row][col + 4]) = fb;
    #pragma unroll
    for (int r = 0; r < 8; ++r) xv[r] = x[(size_t)(p0 + r) * T_ + 1];
  }
  __syncthreads();  // prologue: one-time stages + xs(0) visible

  // g1 for t=0 (p=1 waves, all lanes, bat = b)
  float g1cur = 0.f;
  if (p) g1cur = g1_compute(&sm.WinT2[il][0], &sm.xs[b][0]);

  for (int t = 0; t < T_; ++t) {
    unsigned* gprev = (t & 1) ? gm0 : gm1;   // s(t-1); t=0 reads zeroed gm1
    unsigned* gcur  = (t & 1) ? gm1 : gm0;
    unsigned (* __restrict__ mk)[65] = sm.maskb[t & 1];

    // ---- load neuron-major ballots + 64x64 bit transpose -> maskb[t&1] ----
    {
      const int i32 = b & 31, hh = b >> 5;
      #pragma unroll
      for (int kk = 0; kk < 4; ++kk) {
        const int k = (wid << 2) | kk;
        unsigned xw = __hip_atomic_load(gprev + (k * 32 + i32) * 2 + hh,
                                        __ATOMIC_RELAXED, __HIP_MEMORY_SCOPE_AGENT);
        BT_ALL(xw);
        mk[b][k] = xw;
      }
    }
    __syncthreads();  // A: mask ready; prev-window G1 reads done (xs reusable)

    // ---- stage xs(t+1) (overwrites xs(t) — no longer live); prefetch ----
    if (t + 1 < T_) {
      const int p0 = tid * 8;
      float4 fa, fb;
      fa.x = xv[0]; fa.y = xv[1]; fa.z = xv[2]; fa.w = xv[3];
      fb.x = xv[4]; fb.y = xv[5]; fb.z = xv[6]; fb.w = xv[7];
      const int row = p0 >> 7, col = p0 & 127;
      *(float4*)(&sm.xs[row][col])     = fa;
      *(float4*)(&sm.xs[row][col + 4]) = fb;
      if (t + 2 < T_) {
        #pragma unroll
        for (int r = 0; r < 8; ++r) xv[r] = x[(size_t)(p0 + r) * T_ + (t + 2)];
      }
    }

    // ---- G2: block blk of bat0 (lo) / bat1 (hi); 2 weight streams/wave ----
    v2f acc; acc.x = 0.f; acc.y = 0.f;
    {
      const float*    wbase = &sm.WtT2[il][blk * WROW];
      const unsigned* mr0   = &mk[bat0][blk * 16];
      const unsigned* mr1   = &mk[bat1][blk * 16];
      #pragma unroll 4
      for (int wq = 0; wq < 16; ++wq) {
        const unsigned m0 = mr0[wq];
        const unsigned m1 = mr1[wq];
        const float4* q = (const float4*)(wbase + wq * 32);
        #pragma unroll
        for (int jq = 0; jq < 8; ++jq) {
          const float4 w4 = q[jq];
          const int jb = jq * 4;
          ACC2(acc, __float_as_uint(w4.x), m0, m1, jb + 0);
          ACC2(acc, __float_as_uint(w4.y), m0, m1, jb + 1);
          ACC2(acc, __float_as_uint(w4.z), m0, m1, jb + 2);
          ACC2(acc, __float_as_uint(w4.w), m0, m1, jb + 3);
        }
      }
    }

    // ---- p=0: fold s01 = rn(b0+b1) (commutative-exact), publish ----
    if (!p) {
      const float shx = __shfl_xor(acc.x, 1);
      const float shy = __shfl_xor(acc.y, 1);
      const float s01x = __fadd_rn(acc.x, shx);   // bat0 pair-sum
      const float s01y = __fadd_rn(acc.y, shy);   // bat1 pair-sum
      // lane b's own batch is b: even lane -> bat0 == b (.x), odd -> bat1 (.y)
      sm.s01buf[il][b] = (b & 1) ? s01y : s01x;
    }
    __syncthreads();  // E: s01buf ready

    // ---- p=1: exact fold tail + LIF + full-64 ballot + 8-B gm store ----
    if (p) {
      const float shx = __shfl_xor(acc.x, 1);
      const float shy = __shfl_xor(acc.y, 1);
      // lane b (bat=b): even: a2 = my acc.x (blk2), a3 = partner .x (blk3)
      //                 odd : a2 = partner .y (blk2), a3 = my acc.y (blk3)
      const float a2 = (b & 1) ? shy : acc.x;
      const float a3 = (b & 1) ? acc.y : shx;
      const float s01 = sm.s01buf[il][b];
      const float g2 = __fadd_rn(__fadd_rn(s01, a2), a3);
      const float I  = __fadd_rn(g1cur, g2);
      v = __fadd_rn(__fmul_rn(0.9f, v), I);
      const bool s = (v >= 1.0f);
      if (s) { v = 0.f; cntr++; }
      const unsigned long long bal = __ballot(s);  // bit b = spike(bat b, iu)
      if (b == 0)
        __hip_atomic_store((unsigned long long*)gcur + iu, bal,
                           __ATOMIC_RELAXED, __HIP_MEMORY_SCOPE_AGENT);
    }
    __syncthreads();  // B: gm stores drained + xs(t+1) staging complete

    // ---- FLAT ARRIVAL: own slot, release store (orders the gm stores) ----
    if (tid == 0)
      __hip_atomic_store(arr + w * 4, (unsigned)(t + 1),
                         __ATOMIC_RELEASE, __HIP_MEMORY_SCOPE_AGENT);

    // ==== POLL WINDOW (off the inter-wg critical path) ====

    // ---- G1(t+1) on p=1 waves (all 64 lanes, bat=b); ordered by B ----
    if (p && t + 1 < T_)
      g1cur = g1_compute(&sm.WinT2[il][0], &sm.xs[b][0]);

    // ---- CHECKER (wg 255, wave 0): poll all 256 slots, then release ----
    if (w == CHKWG && wid == 0) {
      const unsigned tgt = (unsigned)(t + 1);
      for (;;) {
        unsigned a0 = __hip_atomic_load(arr + (b +   0) * 4, __ATOMIC_RELAXED,
                                        __HIP_MEMORY_SCOPE_AGENT);
        unsigned a1 = __hip_atomic_load(arr + (b +  64) * 4, __ATOMIC_RELAXED,
                                        __HIP_MEMORY_SCOPE_AGENT);
        unsigned a2c = __hip_atomic_load(arr + (b + 128) * 4, __ATOMIC_RELAXED,
                                         __HIP_MEMORY_SCOPE_AGENT);
        unsigned a3c = __hip_atomic_load(arr + (b + 192) * 4, __ATOMIC_RELAXED,
                                         __HIP_MEMORY_SCOPE_AGENT);
        bool ok = (a0 >= tgt) & (a1 >= tgt) & (a2c >= tgt) & (a3c >= tgt);
        if (__all(ok)) break;
        __builtin_amdgcn_s_sleep(1);
      }
      if (b < NFLAG)
        __hip_atomic_store(flgb + b * 256, (unsigned)(t + 1),
                           __ATOMIC_RELEASE, __HIP_MEMORY_SCOPE_AGENT);
    }

    // ---- classifier (wg w<64) on the otherwise-idle p=0 waves ----
    if (w < B_) {
      if (!p) {
        for (int c = wid; c < NCLS; c += 8) {
          double pc = 0.0;
          if (t > 0) {
            const float* __restrict__ wc = Wclf + (size_t)c * NRES + b;
            #pragma unroll 4
            for (int q = 0; q < 32; ++q) {
              const unsigned mw = mk[w][(b >> 5) + 2 * q];
              const float wv = wc[q * 64];
              const unsigned keep =
                  (unsigned)(((int)(mw << (31 - (b & 31)))) >> 31);
              pc += (double)__uint_as_float(keep & __float_as_uint(wv));
            }
          }
          #pragma unroll
          for (int off = 1; off < 64; off <<= 1)
            pc += __shfl_xor(pc, off, 64);
          if (b == 0) sm.clfred2[t & 1][c] = pc;
        }
      }
      // consume PREV step's partial (written window t-1; ordered by barriers)
      if (tid < NCLS && t >= 2) {
        vc = 0.9 * vc + sm.clfred2[(t + 1) & 1][tid];
        if (vc >= 1.0) { vc = 0.0; cntc++; }
      }
    }

    // ---- PER-WAVE flag poll (all wgs; no extra barrier) ----
    while (__hip_atomic_load(myflag, __ATOMIC_RELAXED,
                             __HIP_MEMORY_SCOPE_AGENT) < (unsigned)(t + 1))
      __builtin_amdgcn_s_sleep(1);
  }

  // ======== epilogue ========
  __syncthreads();  // order window-499 clfred2 writes before E1 reads
  // E1: deferred consume of partials written at t=499 (s(498), buf 1)
  if (w < B_ && tid < NCLS) {
    vc = 0.9 * vc + sm.clfred2[1][tid];
    if (vc >= 1.0) { vc = 0.0; cntc++; }
  }
  // E2: transpose s(499) (in gm1 since 499&1==1) -> maskb[0]
  {
    const int i32 = b & 31, hh = b >> 5;
    #pragma unroll
    for (int kk = 0; kk < 4; ++kk) {
      const int k = (wid << 2) | kk;
      unsigned xw = __hip_atomic_load(gm1 + (k * 32 + i32) * 2 + hh,
                                      __ATOMIC_RELAXED, __HIP_MEMORY_SCOPE_AGENT);
      BT_ALL(xw);
      sm.maskb[0][b][k] = xw;
    }
  }
  __syncthreads();
  // E3: classifier partials for s(499) -> clfred2[0]
  if (w < B_ && wid < NCLS) {
    double pc = 0.0;
    {
      const float* __restrict__ wc = Wclf + (size_t)wid * NRES + b;
      #pragma unroll 4
      for (int q = 0; q < 32; ++q) {
        const unsigned mw = sm.maskb[0][w][(b >> 5) + 2 * q];
        const float wv = wc[q * 64];
        const unsigned keep =
            (unsigned)(((int)(mw << (31 - (b & 31)))) >> 31);
        pc += (double)__uint_as_float(keep & __float_as_uint(wv));
      }
    }
    #pragma unroll
    for (int off = 1; off < 64; off <<= 1)
      pc += __shfl_xor(pc, off, 64);
    if (b == 0) sm.clfred2[0][wid] = pc;
  }
  __syncthreads();
  // E4: final classifier LIF (s(499)) + output
  if (w < B_ && tid < NCLS) {
    vc = 0.9 * vc + sm.clfred2[0][tid];
    if (vc >= 1.0) cntc++;
    out[w * NCLS + tid] = (float)cntc;
  }
  // E5: reservoir spike counts: p=1 wave (il), lane b owns (bat b, iu)
  if (p)
    out[B_ * NCLS + (size_t)b * NRES + w * SL + il] = (float)cntr;
}

extern "C" void kernel_launch(void* const* d_in, const int* in_sizes, int n_in,
                              void* d_out, int out_size, void* d_ws, size_t ws_size,
                              hipStream_t stream) {
  const float* x    = (const float*)d_in[0];   // (B, C, T)
  const float* Win  = (const float*)d_in[1];   // (NRES, C)
  const float* Wres = (const float*)d_in[2];   // (NRES, NRES)
  const float* Wclf = (const float*)d_in[3];   // (NCLS, NRES)
  float* out = (float*)d_out;
  unsigned char* ws = (unsigned char*)d_ws;

  hipLaunchKernelGGL(zero_ws_kernel, dim3((WS_WORDS + 255) / 256), dim3(256), 0, stream,
                     (unsigned*)ws, WS_WORDS);
  hipLaunchKernelGGL(reservoir_kernel, dim3(NWG), dim3(NT), 0, stream,
                     x, Win, Wres, Wclf, out, ws);
}